// Round 1
// baseline (54.597 us; speedup 1.0000x reference)
//
#include <hip/hip_runtime.h>
#include <cstdint>

#define N_NEWS 100000
#define QN 1024
#define HDIM 64
#define DN 128
#define E_LINKS 1600000

// ws layout (bytes):
//   slotmap: int[N_NEWS]      @ 0        (400000 B)
//   cs:      float[128]       @ 400384
//   cd:      float[128]       @ 400896
//   den:     float[QN]        @ 401408
//   num:     float[QN*HDIM]   @ 405504   (262144 B) -> total 667648 B

__global__ void k_init(const float* __restrict__ ws_s, const float* __restrict__ ws_d,
                       const float* __restrict__ a_s, const float* __restrict__ a_d,
                       int* __restrict__ slotmap, float* __restrict__ cs, float* __restrict__ cd,
                       float* __restrict__ den, float* __restrict__ num) {
  int i = blockIdx.x * blockDim.x + threadIdx.x;
  if (i < N_NEWS) slotmap[i] = 0x7fffffff;
  if (i < QN * HDIM) num[i] = 0.0f;
  if (i < QN) den[i] = 0.0f;
  if (i < DN) {
    float s = 0.f, d = 0.f;
    for (int h = 0; h < HDIM; ++h) {
      s += a_s[h] * ws_s[h * DN + i];
      d += a_d[h] * ws_d[h * DN + i];
    }
    cs[i] = s; cd[i] = d;
  }
}

__global__ void k_mark(const int* __restrict__ news_idx, const int* __restrict__ n_id,
                       int* __restrict__ slotmap) {
  int q = blockIdx.x * blockDim.x + threadIdx.x;
  if (q >= QN) return;
  int g = news_idx[q];
  int lo = 0, hi = N_NEWS;                      // searchsorted(n_id, g)
  while (lo < hi) { int mid = (lo + hi) >> 1; if (n_id[mid] < g) lo = mid + 1; else hi = mid; }
  atomicMin(&slotmap[lo], q);
}

__global__ __launch_bounds__(256) void k_edges(
    const float* __restrict__ x, const int* __restrict__ esrc, const int* __restrict__ edst,
    const float* __restrict__ wmat, const int* __restrict__ slotmap,
    const float* __restrict__ cs, const float* __restrict__ cd,
    float* __restrict__ den, float* __restrict__ num) {
  __shared__ float4 ws4[HDIM * 32];   // gat_n_ws, 64x128 f32 = 32 KiB
  __shared__ float4 x4[4][32];        // per-wave x[src] row (512 B each)
  const float4* wg4 = (const float4*)wmat;
  for (int t = threadIdx.x; t < HDIM * 32; t += blockDim.x) ws4[t] = wg4[t];
  __syncthreads();

  const int lane = threadIdx.x & 63;
  const int wid  = threadIdx.x >> 6;
  const float csl0 = cs[lane], csl1 = cs[64 + lane];
  const float cdl0 = cd[lane], cdl1 = cd[64 + lane];
  float* xw = (float*)(&x4[wid][0]);

  const long gw = (long)blockIdx.x * (blockDim.x >> 6) + wid;
  const long nw = (long)gridDim.x * (blockDim.x >> 6);
  for (long base = gw * 64; base < E_LINKS; base += nw * 64) {
    long i = base + lane;
    int s = 0, d = 0, slot = 0x7fffffff;
    if (i < E_LINKS) { s = esrc[i]; d = edst[i]; slot = slotmap[d]; }
    unsigned long long mask = __ballot(slot != 0x7fffffff);
    while (mask) {
      int b = __ffsll((unsigned long long)mask) - 1;
      mask &= (mask - 1);
      int es_ = __shfl(s, b), ed_ = __shfl(d, b), sl_ = __shfl(slot, b);
      // cooperative 128-dot logits: e = x[src].cs + x[dst].cd
      float xs0 = x[es_ * DN + lane],      xs1 = x[es_ * DN + 64 + lane];
      float xd0 = x[ed_ * DN + lane],      xd1 = x[ed_ * DN + 64 + lane];
      float ep = xs0 * csl0 + xs1 * csl1 + xd0 * cdl0 + xd1 * cdl1;
      #pragma unroll
      for (int off = 32; off; off >>= 1) ep += __shfl_xor(ep, off);
      float e = ep > 0.f ? ep : 0.2f * ep;        // leaky_relu(., 0.2)
      float w = __expf(e);                        // no max-subtract: |e| small, ratio-invariant
      // stage x[src] row to this wave's LDS slice
      xw[lane] = xs0; xw[64 + lane] = xs1;
      asm volatile("s_waitcnt lgkmcnt(0)" ::: "memory");
      // lane h: hs[h] = dot(x[src], W_s[h,:]); rotated j-order -> conflict-free b128 reads
      float hs = 0.f;
      #pragma unroll 8
      for (int j0 = 0; j0 < 32; ++j0) {
        int jj = (j0 + lane) & 31;
        float4 xv = x4[wid][jj];
        float4 wv = ws4[(lane << 5) + jj];
        hs += xv.x * wv.x + xv.y * wv.y + xv.z * wv.z + xv.w * wv.w;
      }
      atomicAdd(&num[sl_ * HDIM + lane], w * hs);
      if (lane == 0) atomicAdd(&den[sl_], w);
    }
  }
}

__global__ __launch_bounds__(64) void k_head(
    const int* __restrict__ news_idx, const int* __restrict__ n_id,
    const int* __restrict__ slotmap, const float* __restrict__ den, const float* __restrict__ num,
    const float* __restrict__ gb, const float* __restrict__ w1, const float* __restrict__ b1,
    const float* __restrict__ w2, const float* __restrict__ b2, float* __restrict__ out) {
  int q = blockIdx.x;
  int t = threadIdx.x;
  __shared__ float hb[HDIM];
  __shared__ float xb[HDIM];
  __shared__ int sslot;
  if (t == 0) {
    int g = news_idx[q];
    int lo = 0, hi = N_NEWS;
    while (lo < hi) { int mid = (lo + hi) >> 1; if (n_id[mid] < g) lo = mid + 1; else hi = mid; }
    sslot = slotmap[lo];
  }
  __syncthreads();
  int slot = sslot;
  float dv = den[slot];
  float h = num[slot * HDIM + t] / fmaxf(dv, 1e-16f) + gb[t];
  hb[t] = h;
  __syncthreads();
  float acc = b1[t];
  #pragma unroll 8
  for (int j = 0; j < HDIM; ++j) acc += hb[j] * w1[t * HDIM + j];
  xb[t] = fmaxf(acc, 0.f);
  __syncthreads();
  if (t < 32) {
    float o = b2[t];
    #pragma unroll 8
    for (int j = 0; j < HDIM; ++j) o += xb[j] * w2[t * HDIM + j];
    out[q * 32 + t] = o;
  }
}

extern "C" void kernel_launch(void* const* d_in, const int* in_sizes, int n_in,
                              void* d_out, int out_size, void* d_ws, size_t ws_size,
                              hipStream_t stream) {
  const float* x_news   = (const float*)d_in[0];
  const float* gat_n_ws = (const float*)d_in[11];
  const float* gat_n_wd = (const float*)d_in[12];
  const float* gat_n_as = (const float*)d_in[13];
  const float* gat_n_ad = (const float*)d_in[14];
  const float* gat_n_b  = (const float*)d_in[15];
  const float* lin1_w   = (const float*)d_in[16];
  const float* lin1_b   = (const float*)d_in[17];
  const float* lin2_w   = (const float*)d_in[18];
  const float* lin2_b   = (const float*)d_in[19];
  const int* links_src  = (const int*)d_in[24];
  const int* links_dst  = (const int*)d_in[25];
  const int* n_id       = (const int*)d_in[26];
  const int* news_idx   = (const int*)d_in[27];

  char* ws = (char*)d_ws;
  int*   slotmap = (int*)(ws + 0);
  float* cs      = (float*)(ws + 400384);
  float* cd      = (float*)(ws + 400896);
  float* den     = (float*)(ws + 401408);
  float* num     = (float*)(ws + 405504);
  float* outp    = (float*)d_out;

  hipLaunchKernelGGL(k_init, dim3((N_NEWS + 255) / 256), dim3(256), 0, stream,
                     gat_n_ws, gat_n_wd, gat_n_as, gat_n_ad, slotmap, cs, cd, den, num);
  hipLaunchKernelGGL(k_mark, dim3((QN + 255) / 256), dim3(256), 0, stream,
                     news_idx, n_id, slotmap);
  hipLaunchKernelGGL(k_edges, dim3(1024), dim3(256), 0, stream,
                     x_news, links_src, links_dst, gat_n_ws, slotmap, cs, cd, den, num);
  hipLaunchKernelGGL(k_head, dim3(QN), dim3(64), 0, stream,
                     news_idx, n_id, slotmap, den, num, gat_n_b, lin1_w, lin1_b, lin2_w, lin2_b, outp);
}

// Round 2
// 44.392 us; speedup vs baseline: 1.2299x; 1.2299x over previous
//
#include <hip/hip_runtime.h>
#include <cstdint>

#define N_NEWS 100000
#define QN 1024
#define HDIM 64
#define DN 128
#define E_LINKS 1600000
#define INF 0x7fffffff

// ws layout (bytes):
//   slotmap: int[N_NEWS]       @ 0        (400000 B)
//   cs:      float[128]        @ 400000
//   cd:      float[128]        @ 400512
//   edq:     float[QN]         @ 401024   (dot(x[g_q], cd))
//   den:     float[QN]         @ 405120
//   xacc:    float[QN*128]     @ 409216   (524288 B) -> total 933504 B

__global__ void k_init(const float* __restrict__ ws_s, const float* __restrict__ ws_d,
                       const float* __restrict__ a_s, const float* __restrict__ a_d,
                       int* __restrict__ slotmap, float* __restrict__ cs, float* __restrict__ cd,
                       float* __restrict__ den, float* __restrict__ xacc) {
  int i = blockIdx.x * blockDim.x + threadIdx.x;
  if (i < N_NEWS) slotmap[i] = INF;
  if (i < QN * DN) xacc[i] = 0.0f;
  if (i < QN) den[i] = 0.0f;
  if (i < DN) {
    float s = 0.f, d = 0.f;
    for (int h = 0; h < HDIM; ++h) {
      s += a_s[h] * ws_s[h * DN + i];
      d += a_d[h] * ws_d[h * DN + i];
    }
    cs[i] = s; cd[i] = d;
  }
}

// one wave per query: searchsorted, mark slot, precompute dst attention term
__global__ __launch_bounds__(256) void k_mark(
    const int* __restrict__ news_idx, const int* __restrict__ n_id,
    const float* __restrict__ x, const float* __restrict__ cd,
    int* __restrict__ slotmap, float* __restrict__ edq) {
  int lane = threadIdx.x & 63;
  int q = blockIdx.x * 4 + (threadIdx.x >> 6);
  if (q >= QN) return;
  int g = news_idx[q];
  int lo = 0, hi = N_NEWS;                      // searchsorted(n_id, g) — uniform across wave
  while (lo < hi) { int mid = (lo + hi) >> 1; if (n_id[mid] < g) lo = mid + 1; else hi = mid; }
  float ep = x[g * DN + lane] * cd[lane] + x[g * DN + 64 + lane] * cd[64 + lane];
  #pragma unroll
  for (int off = 32; off; off >>= 1) ep += __shfl_xor(ep, off);
  if (lane == 0) {
    edq[q] = ep;
    atomicMin(&slotmap[lo], q);
  }
}

__global__ __launch_bounds__(256) void k_edges(
    const float* __restrict__ x, const int* __restrict__ esrc, const int* __restrict__ edst,
    const int* __restrict__ slotmap, const float* __restrict__ cs,
    const float* __restrict__ edq, float* __restrict__ den, float* __restrict__ xacc) {
  const int lane = threadIdx.x & 63;
  const int wid  = threadIdx.x >> 6;
  const float csl0 = cs[lane], csl1 = cs[64 + lane];

  const long gw = (long)blockIdx.x * 4 + wid;
  const long nw = (long)gridDim.x * 4;
  for (long base = gw * 64; base < E_LINKS; base += nw * 64) {
    long i = base + lane;
    int s = 0, slot = INF;
    if (i < E_LINKS) { s = esrc[i]; slot = slotmap[edst[i]]; }
    unsigned long long mask = __ballot(slot != INF);
    while (mask) {
      int b = __ffsll((unsigned long long)mask) - 1;
      mask &= (mask - 1);
      int es_ = __shfl(s, b), sl_ = __shfl(slot, b);
      float xs0 = x[es_ * DN + lane], xs1 = x[es_ * DN + 64 + lane];
      float ep = xs0 * csl0 + xs1 * csl1;
      #pragma unroll
      for (int off = 32; off; off >>= 1) ep += __shfl_xor(ep, off);
      float e = ep + edq[sl_];                     // uniform scalar load
      e = e > 0.f ? e : 0.2f * e;                  // leaky_relu(., 0.2)
      float w = __expf(e);                         // no max-subtract: ratio-invariant, |e| small
      atomicAdd(&xacc[sl_ * DN + lane], w * xs0);
      atomicAdd(&xacc[sl_ * DN + 64 + lane], w * xs1);
      if (lane == 0) atomicAdd(&den[sl_], w);
    }
  }
}

__global__ __launch_bounds__(64) void k_head(
    const int* __restrict__ news_idx, const int* __restrict__ n_id,
    const int* __restrict__ slotmap, const float* __restrict__ den,
    const float* __restrict__ xacc, const float* __restrict__ wsmat,
    const float* __restrict__ gb, const float* __restrict__ w1, const float* __restrict__ b1,
    const float* __restrict__ w2, const float* __restrict__ b2, float* __restrict__ out) {
  int q = blockIdx.x;
  int t = threadIdx.x;
  __shared__ float xr[DN];
  __shared__ float hb[HDIM];
  __shared__ float xb[HDIM];
  int g = news_idx[q];                            // uniform search
  int lo = 0, hi = N_NEWS;
  while (lo < hi) { int mid = (lo + hi) >> 1; if (n_id[mid] < g) lo = mid + 1; else hi = mid; }
  int slot = slotmap[lo];
  xr[t] = xacc[slot * DN + t];
  xr[64 + t] = xacc[slot * DN + 64 + t];
  __syncthreads();
  float dv = fmaxf(den[slot], 1e-16f);
  // h = (W_s @ xacc)/den + b   (num/den with num = W_s @ sum(w*x[src]))
  const float4* wr = (const float4*)(wsmat + t * DN);
  const float4* xr4 = (const float4*)xr;
  float acc = 0.f;
  #pragma unroll 8
  for (int j = 0; j < 32; ++j) {
    float4 wv = wr[j], xv = xr4[j];
    acc += wv.x * xv.x + wv.y * xv.y + wv.z * xv.z + wv.w * xv.w;
  }
  hb[t] = acc / dv + gb[t];
  __syncthreads();
  float a1 = b1[t];
  #pragma unroll 8
  for (int j = 0; j < HDIM; ++j) a1 += hb[j] * w1[t * HDIM + j];
  xb[t] = fmaxf(a1, 0.f);
  __syncthreads();
  if (t < 32) {
    float o = b2[t];
    #pragma unroll 8
    for (int j = 0; j < HDIM; ++j) o += xb[j] * w2[t * HDIM + j];
    out[q * 32 + t] = o;
  }
}

extern "C" void kernel_launch(void* const* d_in, const int* in_sizes, int n_in,
                              void* d_out, int out_size, void* d_ws, size_t ws_size,
                              hipStream_t stream) {
  const float* x_news   = (const float*)d_in[0];
  const float* gat_n_ws = (const float*)d_in[11];
  const float* gat_n_wd = (const float*)d_in[12];
  const float* gat_n_as = (const float*)d_in[13];
  const float* gat_n_ad = (const float*)d_in[14];
  const float* gat_n_b  = (const float*)d_in[15];
  const float* lin1_w   = (const float*)d_in[16];
  const float* lin1_b   = (const float*)d_in[17];
  const float* lin2_w   = (const float*)d_in[18];
  const float* lin2_b   = (const float*)d_in[19];
  const int* links_src  = (const int*)d_in[24];
  const int* links_dst  = (const int*)d_in[25];
  const int* n_id       = (const int*)d_in[26];
  const int* news_idx   = (const int*)d_in[27];

  char* ws = (char*)d_ws;
  int*   slotmap = (int*)(ws + 0);
  float* cs      = (float*)(ws + 400000);
  float* cd      = (float*)(ws + 400512);
  float* edq     = (float*)(ws + 401024);
  float* den     = (float*)(ws + 405120);
  float* xacc    = (float*)(ws + 409216);
  float* outp    = (float*)d_out;

  hipLaunchKernelGGL(k_init, dim3((QN * DN + 255) / 256), dim3(256), 0, stream,
                     gat_n_ws, gat_n_wd, gat_n_as, gat_n_ad, slotmap, cs, cd, den, xacc);
  hipLaunchKernelGGL(k_mark, dim3(QN / 4), dim3(256), 0, stream,
                     news_idx, n_id, x_news, cd, slotmap, edq);
  hipLaunchKernelGGL(k_edges, dim3(2048), dim3(256), 0, stream,
                     x_news, links_src, links_dst, slotmap, cs, edq, den, xacc);
  hipLaunchKernelGGL(k_head, dim3(QN), dim3(64), 0, stream,
                     news_idx, n_id, slotmap, den, xacc, gat_n_ws,
                     gat_n_b, lin1_w, lin1_b, lin2_w, lin2_b, outp);
}